// Round 1
// baseline (597.664 us; speedup 1.0000x reference)
//
#include <hip/hip_runtime.h>
#include <math.h>

#define N_TOK 8192
#define DIM   1024
#define NEXP  8
#define HID   4096
#define CAP   1024
#define TPT   (N_TOK / 256)
#define RT_BLOCKS 1024
#define RT_TPB 8                 // tokens per router block (2 per wave)

typedef _Float16 f16x8 __attribute__((ext_vector_type(8)));
typedef _Float16 f16x4 __attribute__((ext_vector_type(4)));
typedef float    f32x4 __attribute__((ext_vector_type(4)));

// tanh-approx GELU: max |diff vs erf-gelu| ~5e-4; after gemm2 (random W2) -> ~2e-4.
__device__ __forceinline__ float gelu_fast(float v) {
    const float v2 = v * v;
    const float u = v * (0.79788456f + 0.035677408136f * v2);  // sqrt(2/pi)*(v+0.044715v^3)
    const float ex = __expf(2.f * u);
    const float th = 1.f - 2.f / (1.f + ex);                   // tanh(u), saturates correctly
    return 0.5f * v * (1.f + th);
}

__device__ __forceinline__ void gl_lds16(const void* g, void* l) {
    __builtin_amdgcn_global_load_lds(
        (const __attribute__((address_space(1))) unsigned int*)g,
        (__attribute__((address_space(3))) unsigned int*)l, 16, 0, 0);
}

// ---------------- router: 1024 blocks, float4 x-loads, per-block partials ----------------
__global__ __launch_bounds__(256) void router_kernel(
    const float* __restrict__ x, const float* __restrict__ Wg,
    int* __restrict__ ei, float* __restrict__ eprob,
    float* __restrict__ pp)            // [RT_BLOCKS][NEXP+1]
{
    __shared__ float psum_s[NEXP + 1];
    const int tid = threadIdx.x;
    const int w = tid >> 6, lane = tid & 63;
    if (tid <= NEXP) psum_s[tid] = 0.f;
    __syncthreads();

    float p_loc[NEXP];
#pragma unroll
    for (int e = 0; e < NEXP; ++e) p_loc[e] = 0.f;
    float z_loc = 0.f;

#pragma unroll
    for (int ti = 0; ti < 2; ++ti) {
        const int t = blockIdx.x * RT_TPB + w * 2 + ti;
        const float* xr = x + (size_t)t * DIM;
        float acc[NEXP];
#pragma unroll
        for (int e = 0; e < NEXP; ++e) acc[e] = 0.f;
#pragma unroll
        for (int k = 0; k < DIM / 256; ++k) {           // 4 iters, independent loads
            const int d = k * 256 + lane * 4;
            const float4 xv = *(const float4*)(xr + d);
            const float xs[4] = {xv.x, xv.y, xv.z, xv.w};
#pragma unroll
            for (int u = 0; u < 4; ++u) {
                const float4 w0 = *(const float4*)(Wg + (size_t)(d + u) * NEXP);
                const float4 w1 = *(const float4*)(Wg + (size_t)(d + u) * NEXP + 4);
                acc[0] += xs[u] * w0.x; acc[1] += xs[u] * w0.y;
                acc[2] += xs[u] * w0.z; acc[3] += xs[u] * w0.w;
                acc[4] += xs[u] * w1.x; acc[5] += xs[u] * w1.y;
                acc[6] += xs[u] * w1.z; acc[7] += xs[u] * w1.w;
            }
        }
#pragma unroll
        for (int off = 32; off > 0; off >>= 1) {
#pragma unroll
            for (int e = 0; e < NEXP; ++e)
                acc[e] += __shfl_down(acc[e], off, 64);
        }
        if (lane == 0) {
            float m = acc[0]; int arg = 0;
#pragma unroll
            for (int e = 1; e < NEXP; ++e) { if (acc[e] > m) { m = acc[e]; arg = e; } }
            float ex[NEXP]; float se = 0.f;
#pragma unroll
            for (int e = 0; e < NEXP; ++e) { ex[e] = expf(acc[e] - m); se += ex[e]; }
            const float lse = m + logf(se);
            const float inv = 1.f / se;
#pragma unroll
            for (int e = 0; e < NEXP; ++e) p_loc[e] += ex[e] * inv;
            z_loc += lse * lse;
            ei[t] = arg;
            eprob[t] = ex[arg] * inv;
        }
    }
    if (lane == 0) {
#pragma unroll
        for (int e = 0; e < NEXP; ++e) atomicAdd(&psum_s[e], p_loc[e]);
        atomicAdd(&psum_s[NEXP], z_loc);
    }
    __syncthreads();
    if (tid <= NEXP) pp[blockIdx.x * (NEXP + 1) + tid] = psum_s[tid];
}

// ---------------- dispatch ----------------
__global__ __launch_bounds__(256) void dispatch_kernel(
    const int* __restrict__ ei, const float* __restrict__ eprob,
    int* __restrict__ slot_to_token, int* __restrict__ sort_idx,
    float* __restrict__ scale,
    const float* __restrict__ pp,      // [RT_BLOCKS][NEXP+1]
    int* __restrict__ dropped, int* __restrict__ n_dropped,
    float* __restrict__ aux_out)
{
    __shared__ int hist[NEXP][256];
    __shared__ int start_s[NEXP];
    __shared__ float red_s[4][NEXP + 1];
    __shared__ float tot_s[NEXP + 1];
    __shared__ int ndrop_s;
    const int t = threadIdx.x;
    const int w = t >> 6, lane = t & 63;
    if (t == 0) ndrop_s = 0;

    // reduce router partials: 1024 blocks -> each thread sums 4
    {
        float v[NEXP + 1];
#pragma unroll
        for (int j = 0; j <= NEXP; ++j) v[j] = 0.f;
        for (int g = 0; g < RT_BLOCKS / 256; ++g)
#pragma unroll
            for (int j = 0; j <= NEXP; ++j) v[j] += pp[(size_t)(g * 256 + t) * (NEXP + 1) + j];
#pragma unroll
        for (int j = 0; j <= NEXP; ++j) {
            float s = v[j];
#pragma unroll
            for (int off = 32; off > 0; off >>= 1) s += __shfl_down(s, off, 64);
            if (lane == 0) red_s[w][j] = s;
        }
    }
    __syncthreads();
    if (t <= NEXP) tot_s[t] = red_s[0][t] + red_s[1][t] + red_s[2][t] + red_s[3][t];
    __syncthreads();

    int le[TPT];
    int lh[NEXP];
#pragma unroll
    for (int e = 0; e < NEXP; ++e) lh[e] = 0;
    const int base = t * TPT;
    for (int i = 0; i < TPT; ++i) {
        const int e = ei[base + i];
        le[i] = e;
        lh[e]++;
    }
#pragma unroll
    for (int e = 0; e < NEXP; ++e) hist[e][t] = lh[e];
    __syncthreads();
    for (int off = 1; off < 256; off <<= 1) {
        int v[NEXP];
#pragma unroll
        for (int e = 0; e < NEXP; ++e) v[e] = (t >= off) ? hist[e][t - off] : 0;
        __syncthreads();
#pragma unroll
        for (int e = 0; e < NEXP; ++e) hist[e][t] += v[e];
        __syncthreads();
    }
    if (t == 0) {
        int s = 0;
        for (int e = 0; e < NEXP; ++e) { start_s[e] = s; s += hist[e][255]; }
    }
    __syncthreads();
    int run[NEXP];
#pragma unroll
    for (int e = 0; e < NEXP; ++e) run[e] = (t > 0) ? hist[e][t - 1] : 0;
    for (int i = 0; i < TPT; ++i) {
        const int n = base + i;
        const int e = le[i];
        const int pos = run[e]++;
        sort_idx[start_s[e] + pos] = n;
        if (pos < CAP) {
            slot_to_token[e * CAP + pos] = n;
        } else {
            const int di = atomicAdd(&ndrop_s, 1);
            dropped[di] = n;
        }
    }
    __syncthreads();
    for (int n = t; n < N_TOK; n += 256) scale[n] = eprob[sort_idx[n]];
    if (t == 0) {
        n_dropped[0] = ndrop_s;
        float s = 0.f;
        for (int e = 0; e < NEXP; ++e) {
            const float f = (float)hist[e][255] / (float)N_TOK;
            const float p = tot_s[e] / (float)N_TOK;
            s += f * p;
        }
        aux_out[0] = 0.01f * (float)NEXP * s + 0.001f * (tot_s[NEXP] / (float)N_TOK);
    }
}

// ---------------- zero only the dropped token rows ----------------
__global__ __launch_bounds__(256) void zero_dropped_kernel(
    const int* __restrict__ dropped, const int* __restrict__ n_dropped,
    float* __restrict__ out)
{
    const int nd = n_dropped[0];
    const float4 z = make_float4(0.f, 0.f, 0.f, 0.f);
    for (int idx = blockIdx.x; idx < nd; idx += gridDim.x) {
        const int tok = dropped[idx];
        *(float4*)(out + (size_t)tok * DIM + threadIdx.x * 4) = z;
    }
}

// ---------------- gather tokens into per-expert fp16 buffer ----------------
__global__ __launch_bounds__(256) void gather_kernel(
    const float* __restrict__ x, const int* __restrict__ slot_to_token,
    _Float16* __restrict__ Xbuf)
{
    const int slot = blockIdx.x;
    const int tok = slot_to_token[slot];
    const int c = threadIdx.x * 4;
    float4 v = make_float4(0.f, 0.f, 0.f, 0.f);
    if (tok >= 0) v = *(const float4*)(x + (size_t)tok * DIM + c);
    f16x4 o;
    o[0] = (_Float16)v.x; o[1] = (_Float16)v.y;
    o[2] = (_Float16)v.z; o[3] = (_Float16)v.w;
    *(f16x4*)(Xbuf + (size_t)slot * DIM + c) = o;
}

// ---------------- fp32 [E][R][C] -> fp16 [E][C][R] transpose ----------------
template<int R, int C>
__global__ __launch_bounds__(256) void transpose_f32_f16(
    const float* __restrict__ in, _Float16* __restrict__ outT)
{
    const int e = blockIdx.z;
    const int r0 = blockIdx.y * 64, c0 = blockIdx.x * 64;
    const float* pin = in + (size_t)e * R * C;
    _Float16* pot = outT + (size_t)e * R * C;
    __shared__ _Float16 tile[64][72];
    const int tid = threadIdx.x;
    const int rr = tid >> 4, cc = (tid & 15) * 4;
#pragma unroll
    for (int ri = 0; ri < 4; ++ri) {
        const int row = rr + ri * 16;
        const float4 v = *(const float4*)&pin[(size_t)(r0 + row) * C + c0 + cc];
        tile[cc + 0][row] = (_Float16)v.x;
        tile[cc + 1][row] = (_Float16)v.y;
        tile[cc + 2][row] = (_Float16)v.z;
        tile[cc + 3][row] = (_Float16)v.w;
    }
    __syncthreads();
    const int c = tid >> 2, rs = (tid & 3) * 16;
    const f16x8 o0 = *(const f16x8*)&tile[c][rs];
    const f16x8 o1 = *(const f16x8*)&tile[c][rs + 8];
    _Float16* po = &pot[(size_t)(c0 + c) * R + r0 + rs];
    *(f16x8*)po = o0;
    *(f16x8*)(po + 8) = o1;
}

// ---------------- MFMA GEMM 1: Hbuf = gelu(Xbuf @ W1 + b1), fp16 ----------------
// BK=64: 8x 16B segments per LDS row -> seg^(row&7) swizzle = 2-way (free) read
// conflicts (BK=32's seg^(row&3) was structurally 4-way). Halves barrier count.
__global__ __launch_bounds__(256) void gemm1_kernel(
    const _Float16* __restrict__ A, const _Float16* __restrict__ Bt,
    const float* __restrict__ b1, _Float16* __restrict__ Hbuf)
{
    // XCD-partitioned block swizzle: each XCD (b&7) owns 4 nb columns -> B L2-resident
    const int b = blockIdx.x;
    const int xcd = b & 7, q = b >> 3;
    const int nb = (xcd << 2) | (q & 3);     // 0..31
    const int mb = q >> 2;                   // 0..63
    const int e  = mb >> 3;
    const _Float16* Ab = A  + (size_t)mb * 128 * DIM;
    const _Float16* Bb = Bt + (size_t)e * HID * DIM + (size_t)nb * 128 * DIM;
    __shared__ _Float16 As[128 * 64];
    __shared__ _Float16 Bs[128 * 64];
    const int tid = threadIdx.x;
    const int lane = tid & 63, w = tid >> 6;
    const int wm = (w >> 1) * 64, wn = (w & 1) * 64;
    const int lr = lane & 15, quad = lane >> 4;

    f32x4 acc[4][4];
#pragma unroll
    for (int i = 0; i < 4; ++i)
#pragma unroll
        for (int j = 0; j < 4; ++j) acc[i][j] = (f32x4)0.f;

    for (int k0 = 0; k0 < DIM; k0 += 64) {
#pragma unroll
        for (int i = 0; i < 4; ++i) {
            const int idx = i * 256 + tid;               // 0..1023 = 128 rows x 8 segs
            const int row = idx >> 3, s = idx & 7;
            const int seg = s ^ (row & 7);               // store-side swizzle
            gl_lds16(Ab + (size_t)row * DIM + k0 + seg * 8, &As[idx * 8]);
            gl_lds16(Bb + (size_t)row * DIM + k0 + seg * 8, &Bs[idx * 8]);
        }
        __syncthreads();
#pragma unroll
        for (int kk = 0; kk < 2; ++kk) {
            f16x8 af[4], bf[4];
#pragma unroll
            for (int i = 0; i < 4; ++i) {
                const int R = wm + i * 16 + lr;
                af[i] = *(const f16x8*)&As[R * 64 + (((kk << 2) | quad) ^ (R & 7)) * 8];
            }
#pragma unroll
            for (int j = 0; j < 4; ++j) {
                const int R = wn + j * 16 + lr;
                bf[j] = *(const f16x8*)&Bs[R * 64 + (((kk << 2) | quad) ^ (R & 7)) * 8];
            }
#pragma unroll
            for (int i = 0; i < 4; ++i)
#pragma unroll
                for (int j = 0; j < 4; ++j)
                    acc[i][j] = __builtin_amdgcn_mfma_f32_16x16x32_f16(af[i], bf[j], acc[i][j], 0, 0, 0);
        }
        __syncthreads();
    }
    float bias[4];
#pragma unroll
    for (int j = 0; j < 4; ++j)
        bias[j] = b1[(size_t)e * HID + (size_t)nb * 128 + wn + j * 16 + lr];
#pragma unroll
    for (int i = 0; i < 4; ++i) {
#pragma unroll
        for (int r = 0; r < 4; ++r) {
            const size_t row = (size_t)mb * 128 + wm + i * 16 + quad * 4 + r;
            _Float16* hr = Hbuf + row * HID + (size_t)nb * 128;
#pragma unroll
            for (int j = 0; j < 4; ++j)
                hr[wn + j * 16 + lr] = (_Float16)gelu_fast(acc[i][j][r] + bias[j]);
        }
    }
}

// ---------------- MFMA GEMM 2: out[tok] = (Hbuf @ W2 + b2) * scale ----------------
// 128x64 tile, BK=64 -> grid 1024 (4 blocks/CU vs old 2): fixes the 21%-occupancy
// grid starvation that left the per-K-step barrier drain unhidden.
__global__ __launch_bounds__(256) void gemm2_kernel(
    const _Float16* __restrict__ A, const _Float16* __restrict__ Bt,
    const float* __restrict__ b2, const int* __restrict__ slot_to_token,
    const float* __restrict__ scale, float* __restrict__ out)
{
    // XCD swizzle: each XCD owns 2 nb columns (2 x 0.5MB of W2t stays L2-resident);
    // A-tiles stream through L3.
    const int b = blockIdx.x;                // 0..1023
    const int xcd = b & 7, q = b >> 3;       // q 0..127
    const int nb = (xcd << 1) | (q & 1);     // 0..15
    const int mb = q >> 1;                   // 0..63
    const int e  = mb >> 3;
    const _Float16* Ab = A  + (size_t)mb * 128 * HID;
    const _Float16* Bb = Bt + (size_t)e * DIM * HID + (size_t)nb * 64 * HID;
    __shared__ _Float16 As[128 * 64];
    __shared__ _Float16 Bs[64 * 64];
    const int tid = threadIdx.x;
    const int lane = tid & 63, w = tid >> 6;
    const int wm = (w >> 1) * 64, wn = (w & 1) * 32;
    const int lr = lane & 15, quad = lane >> 4;

    f32x4 acc[4][2];
#pragma unroll
    for (int i = 0; i < 4; ++i)
#pragma unroll
        for (int j = 0; j < 2; ++j) acc[i][j] = (f32x4)0.f;

    for (int k0 = 0; k0 < HID; k0 += 64) {
#pragma unroll
        for (int i = 0; i < 4; ++i) {
            const int idx = i * 256 + tid;               // 0..1023 = 128 rows x 8 segs
            const int row = idx >> 3, s = idx & 7;
            const int seg = s ^ (row & 7);
            gl_lds16(Ab + (size_t)row * HID + k0 + seg * 8, &As[idx * 8]);
        }
#pragma unroll
        for (int i = 0; i < 2; ++i) {
            const int idx = i * 256 + tid;               // 0..511 = 64 rows x 8 segs
            const int row = idx >> 3, s = idx & 7;
            const int seg = s ^ (row & 7);
            gl_lds16(Bb + (size_t)row * HID + k0 + seg * 8, &Bs[idx * 8]);
        }
        __syncthreads();
#pragma unroll
        for (int kk = 0; kk < 2; ++kk) {
            f16x8 af[4], bf[2];
#pragma unroll
            for (int i = 0; i < 4; ++i) {
                const int R = wm + i * 16 + lr;
                af[i] = *(const f16x8*)&As[R * 64 + (((kk << 2) | quad) ^ (R & 7)) * 8];
            }
#pragma unroll
            for (int j = 0; j < 2; ++j) {
                const int R = wn + j * 16 + lr;
                bf[j] = *(const f16x8*)&Bs[R * 64 + (((kk << 2) | quad) ^ (R & 7)) * 8];
            }
#pragma unroll
            for (int i = 0; i < 4; ++i)
#pragma unroll
                for (int j = 0; j < 2; ++j)
                    acc[i][j] = __builtin_amdgcn_mfma_f32_16x16x32_f16(af[i], bf[j], acc[i][j], 0, 0, 0);
        }
        __syncthreads();
    }
    float bias[2];
#pragma unroll
    for (int j = 0; j < 2; ++j)
        bias[j] = b2[(size_t)e * DIM + (size_t)nb * 64 + wn + j * 16 + lr];
#pragma unroll
    for (int i = 0; i < 4; ++i) {
#pragma unroll
        for (int r = 0; r < 4; ++r) {
            const int slot = mb * 128 + wm + i * 16 + quad * 4 + r;
            const int tok = slot_to_token[slot];
            if (tok >= 0) {
                const float sc = scale[tok];
                float* orow = out + (size_t)tok * DIM + (size_t)nb * 64;
#pragma unroll
                for (int j = 0; j < 2; ++j)
                    orow[wn + j * 16 + lr] = (acc[i][j][r] + bias[j]) * sc;
            }
        }
    }
}

extern "C" void kernel_launch(void* const* d_in, const int* in_sizes, int n_in,
                              void* d_out, int out_size, void* d_ws, size_t ws_size,
                              hipStream_t stream)
{
    const float* x  = (const float*)d_in[0];
    const float* Wg = (const float*)d_in[1];
    const float* W1 = (const float*)d_in[2];
    const float* b1 = (const float*)d_in[3];
    const float* W2 = (const float*)d_in[4];
    const float* b2 = (const float*)d_in[5];
    float* out = (float*)d_out;

    _Float16* Wt   = (_Float16*)d_ws;                         // 64 MB (W1t, later W2t)
    _Float16* Xbuf = Wt + (size_t)NEXP * HID * DIM;           // 16 MB
    _Float16* Hbuf = Xbuf + (size_t)N_TOK * DIM;              // 64 MB
    int*   ei    = (int*)(Hbuf + (size_t)N_TOK * HID);
    float* eprob = (float*)(ei + N_TOK);
    int*   sort_idx = (int*)(eprob + N_TOK);
    float* scale = (float*)(sort_idx + N_TOK);
    int*   s2t   = (int*)(scale + N_TOK);
    float* pp    = (float*)(s2t + NEXP * CAP);                // [1024][9]
    int*   dropped = (int*)(pp + RT_BLOCKS * (NEXP + 1));     // [8192]
    int*   n_dropped = dropped + N_TOK;                       // [1]

    hipMemsetAsync(s2t, 0xFF, (size_t)NEXP * CAP * sizeof(int), stream);

    transpose_f32_f16<DIM, HID><<<dim3(HID / 64, DIM / 64, NEXP), 256, 0, stream>>>(W1, Wt);
    router_kernel<<<RT_BLOCKS, 256, 0, stream>>>(x, Wg, ei, eprob, pp);
    dispatch_kernel<<<1, 256, 0, stream>>>(ei, eprob, s2t, sort_idx, scale,
                                           pp, dropped, n_dropped,
                                           out + (size_t)N_TOK * DIM);
    zero_dropped_kernel<<<128, 256, 0, stream>>>(dropped, n_dropped, out);
    gather_kernel<<<NEXP * CAP, 256, 0, stream>>>(x, s2t, Xbuf);
    gemm1_kernel<<<2048, 256, 0, stream>>>(Xbuf, Wt, b1, Hbuf);
    transpose_f32_f16<HID, DIM><<<dim3(DIM / 64, HID / 64, NEXP), 256, 0, stream>>>(W2, Wt);
    gemm2_kernel<<<1024, 256, 0, stream>>>(Hbuf, Wt, b2, s2t, scale, out);
}

// Round 2
// 591.999 us; speedup vs baseline: 1.0096x; 1.0096x over previous
//
#include <hip/hip_runtime.h>
#include <math.h>

#define N_TOK 8192
#define DIM   1024
#define NEXP  8
#define HID   4096
#define CAP   1024
#define TPT   (N_TOK / 256)
#define RT_BLOCKS 1024
#define RT_TPB 8                 // tokens per router block (2 per wave)

typedef _Float16 f16x8 __attribute__((ext_vector_type(8)));
typedef _Float16 f16x4 __attribute__((ext_vector_type(4)));
typedef float    f32x4 __attribute__((ext_vector_type(4)));

// tanh-approx GELU: max |diff vs erf-gelu| ~5e-4; after gemm2 (random W2) -> ~2e-4.
__device__ __forceinline__ float gelu_fast(float v) {
    const float v2 = v * v;
    const float u = v * (0.79788456f + 0.035677408136f * v2);  // sqrt(2/pi)*(v+0.044715v^3)
    const float ex = __expf(2.f * u);
    const float th = 1.f - 2.f / (1.f + ex);                   // tanh(u), saturates correctly
    return 0.5f * v * (1.f + th);
}

__device__ __forceinline__ void gl_lds16(const void* g, void* l) {
    __builtin_amdgcn_global_load_lds(
        (const __attribute__((address_space(1))) unsigned int*)g,
        (__attribute__((address_space(3))) unsigned int*)l, 16, 0, 0);
}

// ---------------- router: 1024 blocks, float4 x-loads, per-block partials ----------------
__global__ __launch_bounds__(256) void router_kernel(
    const float* __restrict__ x, const float* __restrict__ Wg,
    int* __restrict__ ei, float* __restrict__ eprob,
    float* __restrict__ pp)            // [RT_BLOCKS][NEXP+1]
{
    __shared__ float psum_s[NEXP + 1];
    const int tid = threadIdx.x;
    const int w = tid >> 6, lane = tid & 63;
    if (tid <= NEXP) psum_s[tid] = 0.f;
    __syncthreads();

    float p_loc[NEXP];
#pragma unroll
    for (int e = 0; e < NEXP; ++e) p_loc[e] = 0.f;
    float z_loc = 0.f;

#pragma unroll
    for (int ti = 0; ti < 2; ++ti) {
        const int t = blockIdx.x * RT_TPB + w * 2 + ti;
        const float* xr = x + (size_t)t * DIM;
        float acc[NEXP];
#pragma unroll
        for (int e = 0; e < NEXP; ++e) acc[e] = 0.f;
#pragma unroll
        for (int k = 0; k < DIM / 256; ++k) {           // 4 iters, independent loads
            const int d = k * 256 + lane * 4;
            const float4 xv = *(const float4*)(xr + d);
            const float xs[4] = {xv.x, xv.y, xv.z, xv.w};
#pragma unroll
            for (int u = 0; u < 4; ++u) {
                const float4 w0 = *(const float4*)(Wg + (size_t)(d + u) * NEXP);
                const float4 w1 = *(const float4*)(Wg + (size_t)(d + u) * NEXP + 4);
                acc[0] += xs[u] * w0.x; acc[1] += xs[u] * w0.y;
                acc[2] += xs[u] * w0.z; acc[3] += xs[u] * w0.w;
                acc[4] += xs[u] * w1.x; acc[5] += xs[u] * w1.y;
                acc[6] += xs[u] * w1.z; acc[7] += xs[u] * w1.w;
            }
        }
#pragma unroll
        for (int off = 32; off > 0; off >>= 1) {
#pragma unroll
            for (int e = 0; e < NEXP; ++e)
                acc[e] += __shfl_down(acc[e], off, 64);
        }
        if (lane == 0) {
            float m = acc[0]; int arg = 0;
#pragma unroll
            for (int e = 1; e < NEXP; ++e) { if (acc[e] > m) { m = acc[e]; arg = e; } }
            float ex[NEXP]; float se = 0.f;
#pragma unroll
            for (int e = 0; e < NEXP; ++e) { ex[e] = expf(acc[e] - m); se += ex[e]; }
            const float lse = m + logf(se);
            const float inv = 1.f / se;
#pragma unroll
            for (int e = 0; e < NEXP; ++e) p_loc[e] += ex[e] * inv;
            z_loc += lse * lse;
            ei[t] = arg;
            eprob[t] = ex[arg] * inv;
        }
    }
    if (lane == 0) {
#pragma unroll
        for (int e = 0; e < NEXP; ++e) atomicAdd(&psum_s[e], p_loc[e]);
        atomicAdd(&psum_s[NEXP], z_loc);
    }
    __syncthreads();
    if (tid <= NEXP) pp[blockIdx.x * (NEXP + 1) + tid] = psum_s[tid];
}

// ---------------- dispatch ----------------
__global__ __launch_bounds__(256) void dispatch_kernel(
    const int* __restrict__ ei, const float* __restrict__ eprob,
    int* __restrict__ slot_to_token, int* __restrict__ sort_idx,
    float* __restrict__ scale,
    const float* __restrict__ pp,      // [RT_BLOCKS][NEXP+1]
    int* __restrict__ dropped, int* __restrict__ n_dropped,
    float* __restrict__ aux_out)
{
    __shared__ int hist[NEXP][256];
    __shared__ int start_s[NEXP];
    __shared__ float red_s[4][NEXP + 1];
    __shared__ float tot_s[NEXP + 1];
    __shared__ int ndrop_s;
    const int t = threadIdx.x;
    const int w = t >> 6, lane = t & 63;
    if (t == 0) ndrop_s = 0;

    // reduce router partials: 1024 blocks -> each thread sums 4
    {
        float v[NEXP + 1];
#pragma unroll
        for (int j = 0; j <= NEXP; ++j) v[j] = 0.f;
        for (int g = 0; g < RT_BLOCKS / 256; ++g)
#pragma unroll
            for (int j = 0; j <= NEXP; ++j) v[j] += pp[(size_t)(g * 256 + t) * (NEXP + 1) + j];
#pragma unroll
        for (int j = 0; j <= NEXP; ++j) {
            float s = v[j];
#pragma unroll
            for (int off = 32; off > 0; off >>= 1) s += __shfl_down(s, off, 64);
            if (lane == 0) red_s[w][j] = s;
        }
    }
    __syncthreads();
    if (t <= NEXP) tot_s[t] = red_s[0][t] + red_s[1][t] + red_s[2][t] + red_s[3][t];
    __syncthreads();

    int le[TPT];
    int lh[NEXP];
#pragma unroll
    for (int e = 0; e < NEXP; ++e) lh[e] = 0;
    const int base = t * TPT;
    for (int i = 0; i < TPT; ++i) {
        const int e = ei[base + i];
        le[i] = e;
        lh[e]++;
    }
#pragma unroll
    for (int e = 0; e < NEXP; ++e) hist[e][t] = lh[e];
    __syncthreads();
    for (int off = 1; off < 256; off <<= 1) {
        int v[NEXP];
#pragma unroll
        for (int e = 0; e < NEXP; ++e) v[e] = (t >= off) ? hist[e][t - off] : 0;
        __syncthreads();
#pragma unroll
        for (int e = 0; e < NEXP; ++e) hist[e][t] += v[e];
        __syncthreads();
    }
    if (t == 0) {
        int s = 0;
        for (int e = 0; e < NEXP; ++e) { start_s[e] = s; s += hist[e][255]; }
    }
    __syncthreads();
    int run[NEXP];
#pragma unroll
    for (int e = 0; e < NEXP; ++e) run[e] = (t > 0) ? hist[e][t - 1] : 0;
    for (int i = 0; i < TPT; ++i) {
        const int n = base + i;
        const int e = le[i];
        const int pos = run[e]++;
        sort_idx[start_s[e] + pos] = n;
        if (pos < CAP) {
            slot_to_token[e * CAP + pos] = n;
        } else {
            const int di = atomicAdd(&ndrop_s, 1);
            dropped[di] = n;
        }
    }
    __syncthreads();
    for (int n = t; n < N_TOK; n += 256) scale[n] = eprob[sort_idx[n]];
    if (t == 0) {
        n_dropped[0] = ndrop_s;
        float s = 0.f;
        for (int e = 0; e < NEXP; ++e) {
            const float f = (float)hist[e][255] / (float)N_TOK;
            const float p = tot_s[e] / (float)N_TOK;
            s += f * p;
        }
        aux_out[0] = 0.01f * (float)NEXP * s + 0.001f * (tot_s[NEXP] / (float)N_TOK);
    }
}

// ---------------- zero only the dropped token rows ----------------
__global__ __launch_bounds__(256) void zero_dropped_kernel(
    const int* __restrict__ dropped, const int* __restrict__ n_dropped,
    float* __restrict__ out)
{
    const int nd = n_dropped[0];
    const float4 z = make_float4(0.f, 0.f, 0.f, 0.f);
    for (int idx = blockIdx.x; idx < nd; idx += gridDim.x) {
        const int tok = dropped[idx];
        *(float4*)(out + (size_t)tok * DIM + threadIdx.x * 4) = z;
    }
}

// ---------------- gather tokens into per-expert fp16 buffer ----------------
__global__ __launch_bounds__(256) void gather_kernel(
    const float* __restrict__ x, const int* __restrict__ slot_to_token,
    _Float16* __restrict__ Xbuf)
{
    const int slot = blockIdx.x;
    const int tok = slot_to_token[slot];
    const int c = threadIdx.x * 4;
    float4 v = make_float4(0.f, 0.f, 0.f, 0.f);
    if (tok >= 0) v = *(const float4*)(x + (size_t)tok * DIM + c);
    f16x4 o;
    o[0] = (_Float16)v.x; o[1] = (_Float16)v.y;
    o[2] = (_Float16)v.z; o[3] = (_Float16)v.w;
    *(f16x4*)(Xbuf + (size_t)slot * DIM + c) = o;
}

// ---------------- fp32 [E][R][C] -> fp16 [E][C][R] transpose ----------------
template<int R, int C>
__global__ __launch_bounds__(256) void transpose_f32_f16(
    const float* __restrict__ in, _Float16* __restrict__ outT)
{
    const int e = blockIdx.z;
    const int r0 = blockIdx.y * 64, c0 = blockIdx.x * 64;
    const float* pin = in + (size_t)e * R * C;
    _Float16* pot = outT + (size_t)e * R * C;
    __shared__ _Float16 tile[64][72];
    const int tid = threadIdx.x;
    const int rr = tid >> 4, cc = (tid & 15) * 4;
#pragma unroll
    for (int ri = 0; ri < 4; ++ri) {
        const int row = rr + ri * 16;
        const float4 v = *(const float4*)&pin[(size_t)(r0 + row) * C + c0 + cc];
        tile[cc + 0][row] = (_Float16)v.x;
        tile[cc + 1][row] = (_Float16)v.y;
        tile[cc + 2][row] = (_Float16)v.z;
        tile[cc + 3][row] = (_Float16)v.w;
    }
    __syncthreads();
    const int c = tid >> 2, rs = (tid & 3) * 16;
    const f16x8 o0 = *(const f16x8*)&tile[c][rs];
    const f16x8 o1 = *(const f16x8*)&tile[c][rs + 8];
    _Float16* po = &pot[(size_t)(c0 + c) * R + r0 + rs];
    *(f16x8*)po = o0;
    *(f16x8*)(po + 8) = o1;
}

// ======================== 8-phase 256-tile MFMA GEMMs ========================
// Structure (T2+T3+T4+T5): 512 threads = 8 waves, BK=64, double-buffered LDS,
// raw s_barrier (no vmcnt drain per phase), stage tile t+1 during phases 0-1 of
// tile t, ONE vmcnt(0)+barrier per K-tile (youngest covered load ~2.5 phases old),
// setprio(1) around each MFMA cluster. Pre-swizzled global source + swizzled
// ds_read (proven conflict-free at BK=64: seg ^ (row&7)).
// Grid: expert-per-XCD (NEXP==8==NXCD): xcd = blockIdx.x & 7 == expert; 4 A-panels
// (2 MB) L2-resident per XCD; each expert's weights touched by exactly one XCD.

// ---------------- GEMM 1: Hbuf = gelu(Xbuf @ W1 + b1)  [256x256, K=1024] ----------------
__global__ __launch_bounds__(512, 2) void gemm1_kernel(
    const _Float16* __restrict__ A, const _Float16* __restrict__ Bt,
    const float* __restrict__ b1, _Float16* __restrict__ Hbuf)
{
    const int b = blockIdx.x;                 // 512 blocks
    const int xcd = b & 7, q = b >> 3;        // q 0..63
    const int mb = (xcd << 2) | (q & 3);      // 0..31 (expert = mb>>2 = xcd)
    const int nb = q >> 2;                    // 0..15
    const int e  = xcd;
    const _Float16* Ab = A  + (size_t)mb * 256 * DIM;
    const _Float16* Bb = Bt + (size_t)e * HID * DIM + (size_t)nb * 256 * DIM;
    __shared__ _Float16 As[2][256 * 64];
    __shared__ _Float16 Bs[2][256 * 64];
    const int tid = threadIdx.x;
    const int lane = tid & 63, w = tid >> 6;
    const int wr = w >> 2, wc = w & 3;        // 2M x 4N waves
    const int lr = lane & 15, quad = lane >> 4;
    const int rb = wr * 128, cb = wc * 64;

    auto stageA = [&](int t, int buf) {
#pragma unroll
        for (int i = 0; i < 4; ++i) {
            const int idx = i * 512 + tid;               // 256 rows x 8 segs
            const int row = idx >> 3, s = idx & 7;
            const int seg = s ^ (row & 7);
            gl_lds16(Ab + (size_t)row * DIM + t * 64 + seg * 8, &As[buf][idx * 8]);
        }
    };
    auto stageB = [&](int t, int buf) {
#pragma unroll
        for (int i = 0; i < 4; ++i) {
            const int idx = i * 512 + tid;
            const int row = idx >> 3, s = idx & 7;
            const int seg = s ^ (row & 7);
            gl_lds16(Bb + (size_t)row * DIM + t * 64 + seg * 8, &Bs[buf][idx * 8]);
        }
    };

    f32x4 acc[8][4];
#pragma unroll
    for (int i = 0; i < 8; ++i)
#pragma unroll
        for (int j = 0; j < 4; ++j) acc[i][j] = (f32x4)0.f;

    stageA(0, 0);
    stageB(0, 0);
    const int NT = DIM / 64;                  // 16
#pragma unroll 2
    for (int t = 0; t < NT; ++t) {
        const int cur = t & 1, nxt = cur ^ 1;
        asm volatile("s_waitcnt vmcnt(0)" ::: "memory");   // tile t staged (per-wave) ...
        __builtin_amdgcn_s_barrier();                      // ... and visible to all waves
#pragma unroll
        for (int ph = 0; ph < 4; ++ph) {
            if (ph == 0 && t + 1 < NT) stageA(t + 1, nxt);
            if (ph == 1 && t + 1 < NT) stageB(t + 1, nxt);
            const int mih = (ph >> 1) * 4, njh = (ph & 1) * 2;
            f16x8 af[4][2], bf[2][2];
#pragma unroll
            for (int mi = 0; mi < 4; ++mi)
#pragma unroll
                for (int kk = 0; kk < 2; ++kk) {
                    const int R = rb + (mih + mi) * 16 + lr;
                    af[mi][kk] = *(const f16x8*)&As[cur][R * 64 + (((kk << 2) | quad) ^ (R & 7)) * 8];
                }
#pragma unroll
            for (int nj = 0; nj < 2; ++nj)
#pragma unroll
                for (int kk = 0; kk < 2; ++kk) {
                    const int R = cb + (njh + nj) * 16 + lr;
                    bf[nj][kk] = *(const f16x8*)&Bs[cur][R * 64 + (((kk << 2) | quad) ^ (R & 7)) * 8];
                }
            __builtin_amdgcn_s_barrier();
            __builtin_amdgcn_s_setprio(1);
#pragma unroll
            for (int kk = 0; kk < 2; ++kk)
#pragma unroll
                for (int mi = 0; mi < 4; ++mi)
#pragma unroll
                    for (int nj = 0; nj < 2; ++nj)
                        acc[mih + mi][njh + nj] = __builtin_amdgcn_mfma_f32_16x16x32_f16(
                            af[mi][kk], bf[nj][kk], acc[mih + mi][njh + nj], 0, 0, 0);
            __builtin_amdgcn_s_setprio(0);
            if (ph < 3) __builtin_amdgcn_s_barrier();
        }
    }

    const int colb = nb * 256 + cb;           // within-expert col base
    float bias[4];
#pragma unroll
    for (int nj = 0; nj < 4; ++nj)
        bias[nj] = b1[(size_t)e * HID + colb + nj * 16 + lr];
#pragma unroll
    for (int mi = 0; mi < 8; ++mi) {
#pragma unroll
        for (int r = 0; r < 4; ++r) {
            const size_t row = (size_t)mb * 256 + rb + mi * 16 + quad * 4 + r;
            _Float16* hr = Hbuf + row * HID + colb;
#pragma unroll
            for (int nj = 0; nj < 4; ++nj)
                hr[nj * 16 + lr] = (_Float16)gelu_fast(acc[mi][nj][r] + bias[nj]);
        }
    }
}

// ---------------- GEMM 2: out[tok] = (Hbuf @ W2 + b2) * scale  [256x128, K=4096] ----------------
__global__ __launch_bounds__(512, 2) void gemm2_kernel(
    const _Float16* __restrict__ A, const _Float16* __restrict__ Bt,
    const float* __restrict__ b2, const int* __restrict__ slot_to_token,
    const float* __restrict__ scale, float* __restrict__ out)
{
    const int b = blockIdx.x;                 // 256 blocks
    const int xcd = b & 7, q = b >> 3;        // q 0..31
    const int mb = (xcd << 2) | (q & 3);      // 0..31 (expert = xcd)
    const int nb = q >> 2;                    // 0..7
    const int e  = xcd;
    const _Float16* Ab = A  + (size_t)mb * 256 * HID;
    const _Float16* Bb = Bt + (size_t)e * DIM * HID + (size_t)nb * 128 * HID;
    __shared__ _Float16 As[2][256 * 64];
    __shared__ _Float16 Bs[2][128 * 64];
    const int tid = threadIdx.x;
    const int lane = tid & 63, w = tid >> 6;
    const int wr = w >> 1, wc = w & 1;        // 4M x 2N waves
    const int lr = lane & 15, quad = lane >> 4;
    const int rb = wr * 64, cb = wc * 64;

    auto stageA = [&](int t, int buf) {
#pragma unroll
        for (int i = 0; i < 4; ++i) {
            const int idx = i * 512 + tid;               // 256 rows x 8 segs
            const int row = idx >> 3, s = idx & 7;
            const int seg = s ^ (row & 7);
            gl_lds16(Ab + (size_t)row * HID + t * 64 + seg * 8, &As[buf][idx * 8]);
        }
    };
    auto stageB = [&](int t, int buf) {
#pragma unroll
        for (int i = 0; i < 2; ++i) {
            const int idx = i * 512 + tid;               // 128 rows x 8 segs
            const int row = idx >> 3, s = idx & 7;
            const int seg = s ^ (row & 7);
            gl_lds16(Bb + (size_t)row * HID + t * 64 + seg * 8, &Bs[buf][idx * 8]);
        }
    };

    f32x4 acc[4][4];
#pragma unroll
    for (int i = 0; i < 4; ++i)
#pragma unroll
        for (int j = 0; j < 4; ++j) acc[i][j] = (f32x4)0.f;

    stageA(0, 0);
    stageB(0, 0);
    const int NT = HID / 64;                  // 64
#pragma unroll 2
    for (int t = 0; t < NT; ++t) {
        const int cur = t & 1, nxt = cur ^ 1;
        asm volatile("s_waitcnt vmcnt(0)" ::: "memory");
        __builtin_amdgcn_s_barrier();
#pragma unroll
        for (int ph = 0; ph < 4; ++ph) {
            if (ph == 0 && t + 1 < NT) stageA(t + 1, nxt);
            if (ph == 1 && t + 1 < NT) stageB(t + 1, nxt);
            const int mih = (ph >> 1) * 2, njh = (ph & 1) * 2;
            f16x8 af[2][2], bf[2][2];
#pragma unroll
            for (int mi = 0; mi < 2; ++mi)
#pragma unroll
                for (int kk = 0; kk < 2; ++kk) {
                    const int R = rb + (mih + mi) * 16 + lr;
                    af[mi][kk] = *(const f16x8*)&As[cur][R * 64 + (((kk << 2) | quad) ^ (R & 7)) * 8];
                }
#pragma unroll
            for (int nj = 0; nj < 2; ++nj)
#pragma unroll
                for (int kk = 0; kk < 2; ++kk) {
                    const int R = cb + (njh + nj) * 16 + lr;
                    bf[nj][kk] = *(const f16x8*)&Bs[cur][R * 64 + (((kk << 2) | quad) ^ (R & 7)) * 8];
                }
            __builtin_amdgcn_s_barrier();
            __builtin_amdgcn_s_setprio(1);
#pragma unroll
            for (int kk = 0; kk < 2; ++kk)
#pragma unroll
                for (int mi = 0; mi < 2; ++mi)
#pragma unroll
                    for (int nj = 0; nj < 2; ++nj)
                        acc[mih + mi][njh + nj] = __builtin_amdgcn_mfma_f32_16x16x32_f16(
                            af[mi][kk], bf[nj][kk], acc[mih + mi][njh + nj], 0, 0, 0);
            __builtin_amdgcn_s_setprio(0);
            if (ph < 3) __builtin_amdgcn_s_barrier();
        }
    }

    const int colb = nb * 128 + cb;           // within-expert col base (0..1023)
    float bias[4];
#pragma unroll
    for (int nj = 0; nj < 4; ++nj)
        bias[nj] = b2[(size_t)e * DIM + colb + nj * 16 + lr];
#pragma unroll
    for (int mi = 0; mi < 4; ++mi) {
#pragma unroll
        for (int r = 0; r < 4; ++r) {
            const int slot = mb * 256 + rb + mi * 16 + quad * 4 + r;
            const int tok = slot_to_token[slot];
            if (tok >= 0) {
                const float sc = scale[tok];
                float* orow = out + (size_t)tok * DIM + colb;
#pragma unroll
                for (int nj = 0; nj < 4; ++nj)
                    orow[nj * 16 + lr] = (acc[mi][nj][r] + bias[nj]) * sc;
            }
        }
    }
}

extern "C" void kernel_launch(void* const* d_in, const int* in_sizes, int n_in,
                              void* d_out, int out_size, void* d_ws, size_t ws_size,
                              hipStream_t stream)
{
    const float* x  = (const float*)d_in[0];
    const float* Wg = (const float*)d_in[1];
    const float* W1 = (const float*)d_in[2];
    const float* b1 = (const float*)d_in[3];
    const float* W2 = (const float*)d_in[4];
    const float* b2 = (const float*)d_in[5];
    float* out = (float*)d_out;

    _Float16* Wt   = (_Float16*)d_ws;                         // 64 MB (W1t, later W2t)
    _Float16* Xbuf = Wt + (size_t)NEXP * HID * DIM;           // 16 MB
    _Float16* Hbuf = Xbuf + (size_t)N_TOK * DIM;              // 64 MB
    int*   ei    = (int*)(Hbuf + (size_t)N_TOK * HID);
    float* eprob = (float*)(ei + N_TOK);
    int*   sort_idx = (int*)(eprob + N_TOK);
    float* scale = (float*)(sort_idx + N_TOK);
    int*   s2t   = (int*)(scale + N_TOK);
    float* pp    = (float*)(s2t + NEXP * CAP);                // [1024][9]
    int*   dropped = (int*)(pp + RT_BLOCKS * (NEXP + 1));     // [8192]
    int*   n_dropped = dropped + N_TOK;                       // [1]

    hipMemsetAsync(s2t, 0xFF, (size_t)NEXP * CAP * sizeof(int), stream);

    transpose_f32_f16<DIM, HID><<<dim3(HID / 64, DIM / 64, NEXP), 256, 0, stream>>>(W1, Wt);
    router_kernel<<<RT_BLOCKS, 256, 0, stream>>>(x, Wg, ei, eprob, pp);
    dispatch_kernel<<<1, 256, 0, stream>>>(ei, eprob, s2t, sort_idx, scale,
                                           pp, dropped, n_dropped,
                                           out + (size_t)N_TOK * DIM);
    zero_dropped_kernel<<<128, 256, 0, stream>>>(dropped, n_dropped, out);
    gather_kernel<<<NEXP * CAP, 256, 0, stream>>>(x, s2t, Xbuf);
    gemm1_kernel<<<512, 512, 0, stream>>>(Xbuf, Wt, b1, Hbuf);
    transpose_f32_f16<HID, DIM><<<dim3(DIM / 64, HID / 64, NEXP), 256, 0, stream>>>(W2, Wt);
    gemm2_kernel<<<256, 512, 0, stream>>>(Hbuf, Wt, b2, s2t, scale, out);
}